// Round 13
// baseline (252.585 us; speedup 1.0000x reference)
//
#include <hip/hip_runtime.h>
#include <hip/hip_cooperative_groups.h>

namespace cg = cooperative_groups;

typedef __attribute__((ext_vector_type(8))) short short8;
typedef __attribute__((ext_vector_type(4))) float f32x4;

#define B_ 16
#define T_ 2000
#define E_ 512
#define A_ 512
#define H_ 4
#define C_ 10
#define KW_ 201
#define KT 576      // 512 enc + 40 conv (4 heads x 10) + 24 zero pad
#define MROWS 2048  // padded T per batch
#define NKT 9       // 576 / 64 K-tiles
#define TP 2048     // padded T for part

__device__ __forceinline__ unsigned short f2bf(float f){
  unsigned int u = __float_as_uint(f);
  u += 0x7FFFu + ((u >> 16) & 1u);   // round-to-nearest-even
  return (unsigned short)(u >> 16);
}
// Pade tanh + clamp; |err|<1e-5 for |x|<2; args here are ~N(0,0.65).
__device__ __forceinline__ float pade_tanh(float x){
  float t = x * x;
  float n = x * fmaf(t, t + 105.f, 945.f);
  float d = fmaf(t, fmaf(t, 15.f, 420.f), 945.f);
  float r = __fdividef(n, d);
  return fminf(1.f, fmaxf(-1.f, r));
}
__device__ __forceinline__ void gl16(const void* g, void* lds){
  __builtin_amdgcn_global_load_lds((const __attribute__((address_space(1))) void*)g,
                                   (__attribute__((address_space(3))) void*)lds, 16, 0, 0);
}
#define DPP_ADD(x, ctrl) do { \
  int _y = __builtin_amdgcn_mov_dpp(__float_as_int(x), (ctrl), 0xf, 0xf, true); \
  (x) += __int_as_float(_y); } while(0)
#define ROW16_SUM(x) do { DPP_ADD(x,0xB1); DPP_ADD(x,0x4E); DPP_ADD(x,0x124); DPP_ADD(x,0x128); } while(0)

// ---------------------------------------------------------------------------
// Fat preprocessing kernel, one launch, disjoint writes:
//   [0,2048)    enc-pack: Abf cols 0..511 (bf16) + zero cols 552..575 (+ full-zero rows >= 2000)
//   [2048,2560) conv: Abf cols 512..551 directly (bf16)
//   [2560,3712) wcomb transpose-pack
//   [3712,3968) dec partials
#define TCH 250
__global__ void k_pre(const float* __restrict__ aw_step, const float* __restrict__ conv_w,
                      const float* __restrict__ We, const float* __restrict__ Wc,
                      unsigned short* __restrict__ Wcomb,
                      const float* __restrict__ dec, const float* __restrict__ Wd,
                      const float* __restrict__ be, float* __restrict__ dech_p,
                      const float* __restrict__ enc, unsigned short* __restrict__ Abf){
  __shared__ float pool[2460];
  int bid = blockIdx.x, tid = threadIdx.x;
  if (bid < 2048){
    // ---- enc-pack
    int b = bid >> 7, r0 = (bid & 127) * 16;
    if (r0 < 2000){
      for (int idx = tid; idx < 16*134; idx += 256){
        int row = idx / 134, g = idx % 134;
        if (g >= 128) g += 10;               // zero-tail cols 552..575
        int t = r0 + row;
        float4 v = make_float4(0.f,0.f,0.f,0.f);
        if (g < 128) v = *(const float4*)&enc[((size_t)b*T_ + t)*E_ + g*4];
        ushort4 u; u.x = f2bf(v.x); u.y = f2bf(v.y); u.z = f2bf(v.z); u.w = f2bf(v.w);
        *(ushort4*)&Abf[((size_t)b*MROWS + t)*KT + g*4] = u;
      }
    } else {
      ushort4 z = {0,0,0,0};
      for (int idx = tid; idx < 16*144; idx += 256){
        int row = idx / 144, g = idx % 144;
        *(ushort4*)&Abf[((size_t)b*MROWS + r0 + row)*KT + g*4] = z;
      }
    }
  } else if (bid < 2560){
    // ---- conv: register sliding window, thread owns 10 t for one channel;
    //      writes bf16 features straight into Abf cols 512..551
    int j = bid - 2048;
    int tc = j & 7, h = (j >> 3) & 3, b = j >> 5;
    int t0 = tc * TCH;
    float* awl = pool;          // [450]
    float* wl  = pool + 450;    // [2010]
    for (int i = tid; i < TCH + 200; i += 256){
      int t = t0 - 100 + i;
      awl[i] = (t >= 0 && t < T_) ? aw_step[((size_t)b*T_ + t)*H_ + h] : 0.f;
    }
    for (int i = tid; i < C_*KW_; i += 256)
      wl[i] = conv_w[(size_t)h*C_*KW_ + i];
    __syncthreads();
    int c = tid % 10, g = tid / 10;
    bool act = g < 25;
    int tb = act ? g * 10 : 0;
    const float* wc = &wl[c * KW_];
    float acc[10], win[10];
    #pragma unroll
    for (int jj = 0; jj < 10; jj++){ acc[jj] = 0.f; win[jj] = awl[tb + jj]; }
    for (int k0 = 0; k0 < 200; k0 += 10){
      #pragma unroll
      for (int u = 0; u < 10; u++){
        float wk = wc[k0 + u];
        #pragma unroll
        for (int jj = 0; jj < 10; jj++)
          acc[jj] = fmaf(win[(jj + u) % 10], wk, acc[jj]);
        win[u] = awl[tb + k0 + u + 10];
      }
    }
    float wk = wc[200];
    #pragma unroll
    for (int jj = 0; jj < 10; jj++)
      acc[jj] = fmaf(win[jj], wk, acc[jj]);
    if (act){
      #pragma unroll
      for (int jj = 0; jj < 10; jj++)
        Abf[((size_t)b*MROWS + t0 + tb + jj)*KT + 512 + h*C_ + c] = f2bf(acc[jj]);
    }
  } else if (bid < 3712){
    // ---- wcomb: Wcomb[n=h*512+a][k] transpose-pack to bf16
    int j = bid - 2560;
    int k0 = (j % 18) * 32, n0 = (j / 18) * 32;
    int h = n0 >> 9, a0 = n0 & 511;
    float (*tt)[33] = (float(*)[33])pool;
    int tx = tid & 31, ty = tid >> 5;   // 32 x 8
    for (int i = ty; i < 32; i += 8){
      int k = k0 + i;
      float v = 0.f;
      if (k < 512) {
        v = We[((size_t)(h*512) + k)*512 + a0 + tx];
      } else if (k < 552) {
        int jj = k - 512, hp = jj / 10, c = jj % 10;
        if (hp == h) v = Wc[(size_t)(h*10 + c)*512 + a0 + tx];
      }
      tt[i][tx] = v;
    }
    __syncthreads();
    for (int i = ty; i < 32; i += 8)
      Wcomb[((size_t)n0 + i)*KT + k0 + tx] = f2bf(tt[tx][i]);
  } else {
    // ---- dec partials: dech_p[dq][b*4+h][a]
    int j = bid - 3712;
    int bh = j & 63, dq = j >> 6;
    int a0 = tid * 2;
    int h = bh & 3;
    float acc0 = 0.f, acc1 = 0.f;
    if (dq == 0){ acc0 = be[h*512 + a0]; acc1 = be[h*512 + a0 + 1]; }
    const float* w = Wd + (size_t)h*512*512 + (size_t)dq*128*512;
    const float* dv = dec + (bh >> 2)*512 + dq*128;
    #pragma unroll 4
    for (int d = 0; d < 128; d++){
      float x = dv[d];
      acc0 = fmaf(x, w[(size_t)d*512 + a0],     acc0);
      acc1 = fmaf(x, w[(size_t)d*512 + a0 + 1], acc1);
    }
    dech_p[((size_t)dq*64 + bh)*512 + a0]     = acc0;
    dech_p[((size_t)dq*64 + bh)*512 + a0 + 1] = acc1;
  }
}

// ---------------------------------------------------------------------------
// 128x128 swizzled TLP GEMM — PINNED ENGINE (round-10 validated: 105 us,
// MfmaUtil 32%, VGPR 64). Round-5/11 A/Bs: 8-phase sched = null, 256-row
// tile = -9%. Do NOT touch structure; do NOT raise launch_bounds min
// (min=5 forced VGPR 48 < 64-reg accumulator -> scratch spill, 107->272 us).
__global__ __launch_bounds__(256, 4) void k_energy(
    const unsigned short* __restrict__ Abf, const unsigned short* __restrict__ Wb,
    const float* __restrict__ dech_p, const float* __restrict__ Vv,
    float* __restrict__ part)
{
  __shared__ __align__(16) unsigned short As[128*64];  // 16 KB
  __shared__ __align__(16) unsigned short Bs[128*64];  // 16 KB

  int hw = blockIdx.x;
  int logical = (hw & 7)*512 + (hw >> 3);   // XCD-contiguous (4096 % 8 == 0)
  int mt = logical >> 4, nt = logical & 15; // mt 0..255, nt 0..15
  int b = mt >> 4;
  int trow = (mt & 15)*128;
  int h = nt >> 2;

  const char* Ag = (const char*)(Abf + ((size_t)b*MROWS + trow)*KT);
  const char* Bg = (const char*)(Wb + (size_t)nt*128*KT);

  int tid = threadIdx.x, lane = tid & 63, w = tid >> 6;  // 4 waves
  int wm = w >> 1, wn = w & 1;

  int srow = tid >> 3;                      // 0..31
  size_t scol = (size_t)(((tid & 7) ^ (srow & 7)) * 16);
  int wub = w * 1024;

  int cx0 = (((lane >> 4) * 16)     ) ^ ((lane & 7) << 4);
  int cx1 = (((lane >> 4) * 16) + 64) ^ ((lane & 7) << 4);
  int arow = (wm*64 + (lane & 15)) * 128;
  int brow = (wn*64 + (lane & 15)) * 128;

  float dv[4], vv[4];
  #pragma unroll
  for (int q = 0; q < 4; q++){
    int a = (nt & 3)*128 + wn*64 + q*16 + (lane & 15);
    int bh = b*4 + h;
    dv[q] = dech_p[((size_t)0*64 + bh)*512 + a] + dech_p[((size_t)1*64 + bh)*512 + a]
          + dech_p[((size_t)2*64 + bh)*512 + a] + dech_p[((size_t)3*64 + bh)*512 + a];
    vv[q] = Vv[h*A_ + a];
  }

  f32x4 acc[4][4];
  #pragma unroll
  for (int m = 0; m < 4; m++)
    #pragma unroll
    for (int q = 0; q < 4; q++) acc[m][q] = (f32x4){0.f,0.f,0.f,0.f};

  for (int ks = 0; ks < NKT; ks++){
    __syncthreads();
    #pragma unroll
    for (int j = 0; j < 4; j++){
      gl16(Ag + (size_t)(j*32 + srow)*(KT*2) + (size_t)ks*128 + scol, (char*)As + j*4096 + wub);
      gl16(Bg + (size_t)(j*32 + srow)*(KT*2) + (size_t)ks*128 + scol, (char*)Bs + j*4096 + wub);
    }
    __syncthreads();
    short8 af[2][4], bf[2][4];
    #pragma unroll
    for (int m = 0; m < 4; m++){
      af[0][m] = *(const short8*)((const char*)As + arow + m*2048 + cx0);
      af[1][m] = *(const short8*)((const char*)As + arow + m*2048 + cx1);
    }
    #pragma unroll
    for (int q = 0; q < 4; q++){
      bf[0][q] = *(const short8*)((const char*)Bs + brow + q*2048 + cx0);
      bf[1][q] = *(const short8*)((const char*)Bs + brow + q*2048 + cx1);
    }
    #pragma unroll
    for (int kk = 0; kk < 2; kk++)
      #pragma unroll
      for (int q = 0; q < 4; q++)
        #pragma unroll
        for (int m = 0; m < 4; m++)
          acc[m][q] = __builtin_amdgcn_mfma_f32_16x16x32_bf16(af[kk][m], bf[kk][q], acc[m][q], 0, 0, 0);
  }

  // epilogue: tanh+V reduce -> ered[wn][tl] (single writer per slot), then
  // wn-merge and one coalesced 128x4B store per block.
  __syncthreads();                    // all LDS reads retired; reuse As
  float* ered = (float*)As;           // [2][128]
  #pragma unroll
  for (int m = 0; m < 4; m++){
    #pragma unroll
    for (int r = 0; r < 4; r++){
      float ps = 0.f;
      #pragma unroll
      for (int q = 0; q < 4; q++)
        ps = fmaf(pade_tanh(acc[m][q][r] + dv[q]), vv[q], ps);
      ROW16_SUM(ps);
      if ((lane & 15) == 0)
        ered[wn*128 + wm*64 + m*16 + (lane >> 4)*4 + r] = ps;
    }
  }
  __syncthreads();
  if (tid < 128){
    int t = trow + tid;
    if (t < T_)
      part[(((size_t)(nt & 3)*16 + b)*H_ + h)*TP + t] = ered[tid] + ered[128 + tid];
  }
}

// ---------------------------------------------------------------------------
// Cooperative post-chain: softmax -> ctxp -> fgemm -> fred with grid.sync()
// between phases. 256 blocks x 256 threads (1/CU, trivially co-resident).
// Phase bodies are byte-identical to the former standalone kernels.
__global__ void k_post(const float* __restrict__ part, const int* __restrict__ x_lens,
                       float* __restrict__ aw, const unsigned short* __restrict__ Abf,
                       float* __restrict__ ctxp, const float* __restrict__ Wm,
                       float* __restrict__ fpart, const float* __restrict__ bm,
                       float* __restrict__ out){
  cg::grid_group grid = cg::this_grid();
  __shared__ float smem[5120];        // union: softmax 2008 | ctxp 500 | fgemm 5120
  int bid = blockIdx.x, tid = threadIdx.x;

  // ---- phase 1: softmax over T per (b,h); blocks 0..63
  if (bid < 64){
    int h = bid & 3, b = bid >> 2;
    float* sh  = smem;                // [2000]
    float* red = smem + 2000;         // [8]
    int xl = x_lens[b];
    float mx = -1e30f;
    for (int t = tid; t < T_; t += 256){
      float e = 0.f;
      if (t < xl){
        e = part[(((size_t)0*16 + b)*H_ + h)*TP + t]
          + part[(((size_t)1*16 + b)*H_ + h)*TP + t]
          + part[(((size_t)2*16 + b)*H_ + h)*TP + t]
          + part[(((size_t)3*16 + b)*H_ + h)*TP + t];
      }
      sh[t] = e;
      mx = fmaxf(mx, e);
    }
    #pragma unroll
    for (int o = 32; o; o >>= 1) mx = fmaxf(mx, __shfl_xor(mx, o));
    if ((tid & 63) == 0) red[tid >> 6] = mx;
    __syncthreads();
    mx = fmaxf(fmaxf(red[0], red[1]), fmaxf(red[2], red[3]));
    float sm = 0.f;
    for (int t = tid; t < T_; t += 256){
      float ex = __expf(sh[t] - mx);
      sh[t] = ex;
      sm += ex;
    }
    #pragma unroll
    for (int o = 32; o; o >>= 1) sm += __shfl_xor(sm, o);
    if ((tid & 63) == 0) red[4 + (tid >> 6)] = sm;
    __syncthreads();
    sm = red[4] + red[5] + red[6] + red[7];
    float inv = 1.f / sm;
    for (int t = tid; t < T_; t += 256){
      aw[((size_t)b*T_ + t)*H_ + h] = sh[t] * inv;
    }
  }
  grid.sync();

  // ---- phase 2: partial context from bf16 Abf; all 256 blocks
  {
    int ch = bid & 15, b = bid >> 4;
    int t0 = ch * 125;
    float* awl = smem;                // [500]
    for (int i = tid; i < 125*4; i += 256)
      awl[i] = aw[((size_t)b*T_ + t0)*H_ + i];
    __syncthreads();
    int e0 = tid * 2;
    float a0x=0,a0y=0,a1x=0,a1y=0,a2x=0,a2y=0,a3x=0,a3y=0;
    #pragma unroll 5
    for (int tl = 0; tl < 125; tl++){
      uint uv = *(const uint*)&Abf[((size_t)b*MROWS + t0 + tl)*KT + e0];
      float evx = __uint_as_float(uv << 16);
      float evy = __uint_as_float(uv & 0xFFFF0000u);
      float w0 = awl[tl*4+0], w1 = awl[tl*4+1], w2 = awl[tl*4+2], w3 = awl[tl*4+3];
      a0x = fmaf(w0, evx, a0x); a0y = fmaf(w0, evy, a0y);
      a1x = fmaf(w1, evx, a1x); a1y = fmaf(w1, evy, a1y);
      a2x = fmaf(w2, evx, a2x); a2y = fmaf(w2, evy, a2y);
      a3x = fmaf(w3, evx, a3x); a3y = fmaf(w3, evy, a3y);
    }
    size_t base = ((size_t)(b*16) + ch) * (H_*E_);
    ctxp[base + 0*E_ + e0] = a0x; ctxp[base + 0*E_ + e0+1] = a0y;
    ctxp[base + 1*E_ + e0] = a1x; ctxp[base + 1*E_ + e0+1] = a1y;
    ctxp[base + 2*E_ + e0] = a2x; ctxp[base + 2*E_ + e0+1] = a2y;
    ctxp[base + 3*E_ + e0] = a3x; ctxp[base + 3*E_ + e0+1] = a3y;
  }
  grid.sync();

  // ---- phase 3: final GEMM partials; all 256 blocks (32 kq x 8 g)
  {
    int kq = bid & 31, g = bid >> 5;
    float* cpl = smem;                // [16][64]
    float* red = smem + 1024;         // [4][16][64]
    {
      int b = tid >> 4, i4 = (tid & 15) * 4;
      const float* base = ctxp + (size_t)b*16*2048 + kq*64 + i4;
      float sx = 0.f, sy = 0.f, sz = 0.f, sw = 0.f;
      #pragma unroll
      for (int ch = 0; ch < 16; ch++){
        float4 v = *(const float4*)(base + (size_t)ch*2048);
        sx += v.x; sy += v.y; sz += v.z; sw += v.w;
      }
      cpl[b*64 + i4] = sx; cpl[b*64 + i4+1] = sy; cpl[b*64 + i4+2] = sz; cpl[b*64 + i4+3] = sw;
    }
    __syncthreads();
    int e = tid & 63, p = tid >> 6;
    float acc[16];
    #pragma unroll
    for (int b = 0; b < 16; b++) acc[b] = 0.f;
    #pragma unroll
    for (int i = 0; i < 16; i++){
      int he = kq*64 + p*16 + i;
      float wv = Wm[(size_t)he*512 + g*64 + e];
      #pragma unroll
      for (int b = 0; b < 16; b++)
        acc[b] = fmaf(cpl[b*64 + p*16 + i], wv, acc[b]);
    }
    #pragma unroll
    for (int b = 0; b < 16; b++) red[(p*16 + b)*64 + e] = acc[b];
    __syncthreads();
    int bq = tid >> 6;          // 0..3
    #pragma unroll
    for (int j = 0; j < 4; j++){
      int b = bq*4 + j;
      float s = red[(0*16 + b)*64 + e] + red[(1*16 + b)*64 + e]
              + red[(2*16 + b)*64 + e] + red[(3*16 + b)*64 + e];
      fpart[(((size_t)kq*16) + b)*512 + g*64 + e] = s;
    }
  }
  grid.sync();

  // ---- phase 4: final reduce; blocks 0..31 (16 b x 2 halves)
  if (bid < 32){
    int b = bid & 15, qq = bid >> 4;
    int eo = qq*256 + tid;
    float acc = bm[eo];
    #pragma unroll 8
    for (int kq = 0; kq < 32; kq++)
      acc += fpart[(((size_t)kq*16) + b)*512 + eo];
    out[(size_t)b*512 + eo] = acc;
  }
}

// ---------------------------------------------------------------------------
extern "C" void kernel_launch(void* const* d_in, const int* in_sizes, int n_in,
                              void* d_out, int out_size, void* d_ws, size_t ws_size,
                              hipStream_t stream){
  const float* enc    = (const float*)d_in[0];
  const int*   xl     = (const int*)  d_in[1];
  const float* dec    = (const float*)d_in[2];
  const float* awstep = (const float*)d_in[3];
  const float* We     = (const float*)d_in[4];
  const float* be     = (const float*)d_in[5];
  const float* Wd     = (const float*)d_in[6];
  const float* Wc     = (const float*)d_in[7];
  const float* convw  = (const float*)d_in[8];
  const float* Vv     = (const float*)d_in[9];
  const float* Wm     = (const float*)d_in[10];
  const float* bm     = (const float*)d_in[11];

  float* out_ctx = (float*)d_out;
  float* out_aw  = (float*)d_out + (size_t)B_ * E_;

  char* ws = (char*)d_ws;
  unsigned short* Wcomb = (unsigned short*)ws; ws += (size_t)2048*KT*2;        //  2,359,296
  unsigned short* Abf   = (unsigned short*)ws; ws += (size_t)B_*MROWS*KT*2;    // 37,748,736
  float* dech_p    = (float*)ws; ws += (size_t)4*64*512*4;                     //    524,288
  float* part      = (float*)ws; ws += (size_t)4*B_*H_*TP*4;                   //  2,097,152
  float* ctxp      = (float*)ws; ws += (size_t)B_*16*H_*E_*4;                  //  2,097,152
  float* fpart     = (float*)ws; ws += (size_t)32*B_*512*4;                    //  1,048,576

  k_pre    <<<dim3(3968), dim3(256), 0, stream>>>(awstep, convw, We, Wc, Wcomb,
                                                  dec, Wd, be, dech_p, enc, Abf);
  k_energy <<<dim3(4096), dim3(256), 0, stream>>>(Abf, Wcomb, dech_p, Vv, part);

  void* args[] = { (void*)&part, (void*)&xl, (void*)&out_aw, (void*)&Abf,
                   (void*)&ctxp, (void*)&Wm, (void*)&fpart, (void*)&bm, (void*)&out_ctx };
  hipLaunchCooperativeKernel((const void*)k_post, dim3(256), dim3(256), args, 0, stream);
}

// Round 14
// 162.914 us; speedup vs baseline: 1.5504x; 1.5504x over previous
//
#include <hip/hip_runtime.h>

typedef __attribute__((ext_vector_type(8))) short short8;
typedef __attribute__((ext_vector_type(4))) float f32x4;

#define B_ 16
#define T_ 2000
#define E_ 512
#define A_ 512
#define H_ 4
#define C_ 10
#define KW_ 201
#define KT 576      // 512 enc + 40 conv (4 heads x 10) + 24 zero pad
#define MROWS 2048  // padded T per batch
#define NKT 9       // 576 / 64 K-tiles
#define TP 2048     // padded T for part

__device__ __forceinline__ unsigned short f2bf(float f){
  unsigned int u = __float_as_uint(f);
  u += 0x7FFFu + ((u >> 16) & 1u);   // round-to-nearest-even
  return (unsigned short)(u >> 16);
}
// Pade tanh + clamp; |err|<1e-5 for |x|<2; args here are ~N(0,0.65).
__device__ __forceinline__ float pade_tanh(float x){
  float t = x * x;
  float n = x * fmaf(t, t + 105.f, 945.f);
  float d = fmaf(t, fmaf(t, 15.f, 420.f), 945.f);
  float r = __fdividef(n, d);
  return fminf(1.f, fmaxf(-1.f, r));
}
__device__ __forceinline__ void gl16(const void* g, void* lds){
  __builtin_amdgcn_global_load_lds((const __attribute__((address_space(1))) void*)g,
                                   (__attribute__((address_space(3))) void*)lds, 16, 0, 0);
}
#define DPP_ADD(x, ctrl) do { \
  int _y = __builtin_amdgcn_mov_dpp(__float_as_int(x), (ctrl), 0xf, 0xf, true); \
  (x) += __int_as_float(_y); } while(0)
#define ROW16_SUM(x) do { DPP_ADD(x,0xB1); DPP_ADD(x,0x4E); DPP_ADD(x,0x124); DPP_ADD(x,0x128); } while(0)

// ---------------------------------------------------------------------------
// Fat preprocessing kernel, one launch, disjoint writes:
//   [0,2048)    enc-pack: Abf cols 0..511 (bf16) + zero cols 552..575 (+ full-zero rows >= 2000)
//   [2048,2560) conv: Abf cols 512..551 directly (bf16)
//   [2560,3712) wcomb transpose-pack
//   [3712,3968) dec partials
#define TCH 250
__global__ void k_pre(const float* __restrict__ aw_step, const float* __restrict__ conv_w,
                      const float* __restrict__ We, const float* __restrict__ Wc,
                      unsigned short* __restrict__ Wcomb,
                      const float* __restrict__ dec, const float* __restrict__ Wd,
                      const float* __restrict__ be, float* __restrict__ dech_p,
                      const float* __restrict__ enc, unsigned short* __restrict__ Abf){
  __shared__ float pool[2460];
  int bid = blockIdx.x, tid = threadIdx.x;
  if (bid < 2048){
    // ---- enc-pack
    int b = bid >> 7, r0 = (bid & 127) * 16;
    if (r0 < 2000){
      for (int idx = tid; idx < 16*134; idx += 256){
        int row = idx / 134, g = idx % 134;
        if (g >= 128) g += 10;               // zero-tail cols 552..575
        int t = r0 + row;
        float4 v = make_float4(0.f,0.f,0.f,0.f);
        if (g < 128) v = *(const float4*)&enc[((size_t)b*T_ + t)*E_ + g*4];
        ushort4 u; u.x = f2bf(v.x); u.y = f2bf(v.y); u.z = f2bf(v.z); u.w = f2bf(v.w);
        *(ushort4*)&Abf[((size_t)b*MROWS + t)*KT + g*4] = u;
      }
    } else {
      ushort4 z = {0,0,0,0};
      for (int idx = tid; idx < 16*144; idx += 256){
        int row = idx / 144, g = idx % 144;
        *(ushort4*)&Abf[((size_t)b*MROWS + r0 + row)*KT + g*4] = z;
      }
    }
  } else if (bid < 2560){
    // ---- conv: register sliding window, thread owns 10 t for one channel;
    //      writes bf16 features straight into Abf cols 512..551
    int j = bid - 2048;
    int tc = j & 7, h = (j >> 3) & 3, b = j >> 5;
    int t0 = tc * TCH;
    float* awl = pool;          // [450]
    float* wl  = pool + 450;    // [2010]
    for (int i = tid; i < TCH + 200; i += 256){
      int t = t0 - 100 + i;
      awl[i] = (t >= 0 && t < T_) ? aw_step[((size_t)b*T_ + t)*H_ + h] : 0.f;
    }
    for (int i = tid; i < C_*KW_; i += 256)
      wl[i] = conv_w[(size_t)h*C_*KW_ + i];
    __syncthreads();
    int c = tid % 10, g = tid / 10;
    bool act = g < 25;
    int tb = act ? g * 10 : 0;
    const float* wc = &wl[c * KW_];
    float acc[10], win[10];
    #pragma unroll
    for (int jj = 0; jj < 10; jj++){ acc[jj] = 0.f; win[jj] = awl[tb + jj]; }
    for (int k0 = 0; k0 < 200; k0 += 10){
      #pragma unroll
      for (int u = 0; u < 10; u++){
        float wk = wc[k0 + u];
        #pragma unroll
        for (int jj = 0; jj < 10; jj++)
          acc[jj] = fmaf(win[(jj + u) % 10], wk, acc[jj]);
        win[u] = awl[tb + k0 + u + 10];
      }
    }
    float wk = wc[200];
    #pragma unroll
    for (int jj = 0; jj < 10; jj++)
      acc[jj] = fmaf(win[jj], wk, acc[jj]);
    if (act){
      #pragma unroll
      for (int jj = 0; jj < 10; jj++)
        Abf[((size_t)b*MROWS + t0 + tb + jj)*KT + 512 + h*C_ + c] = f2bf(acc[jj]);
    }
  } else if (bid < 3712){
    // ---- wcomb: Wcomb[n=h*512+a][k] transpose-pack to bf16
    int j = bid - 2560;
    int k0 = (j % 18) * 32, n0 = (j / 18) * 32;
    int h = n0 >> 9, a0 = n0 & 511;
    float (*tt)[33] = (float(*)[33])pool;
    int tx = tid & 31, ty = tid >> 5;   // 32 x 8
    for (int i = ty; i < 32; i += 8){
      int k = k0 + i;
      float v = 0.f;
      if (k < 512) {
        v = We[((size_t)(h*512) + k)*512 + a0 + tx];
      } else if (k < 552) {
        int jj = k - 512, hp = jj / 10, c = jj % 10;
        if (hp == h) v = Wc[(size_t)(h*10 + c)*512 + a0 + tx];
      }
      tt[i][tx] = v;
    }
    __syncthreads();
    for (int i = ty; i < 32; i += 8)
      Wcomb[((size_t)n0 + i)*KT + k0 + tx] = f2bf(tt[tx][i]);
  } else {
    // ---- dec partials: dech_p[dq][b*4+h][a]
    int j = bid - 3712;
    int bh = j & 63, dq = j >> 6;
    int a0 = tid * 2;
    int h = bh & 3;
    float acc0 = 0.f, acc1 = 0.f;
    if (dq == 0){ acc0 = be[h*512 + a0]; acc1 = be[h*512 + a0 + 1]; }
    const float* w = Wd + (size_t)h*512*512 + (size_t)dq*128*512;
    const float* dv = dec + (bh >> 2)*512 + dq*128;
    #pragma unroll 4
    for (int d = 0; d < 128; d++){
      float x = dv[d];
      acc0 = fmaf(x, w[(size_t)d*512 + a0],     acc0);
      acc1 = fmaf(x, w[(size_t)d*512 + a0 + 1], acc1);
    }
    dech_p[((size_t)dq*64 + bh)*512 + a0]     = acc0;
    dech_p[((size_t)dq*64 + bh)*512 + a0 + 1] = acc1;
  }
}

// ---------------------------------------------------------------------------
// 128x128 swizzled TLP GEMM — PINNED ENGINE (round-10 validated: 105 us,
// MfmaUtil 32%, VGPR 64). Round-5/11/13 A/Bs: 8-phase sched = null, 256-row
// tile = -9%, cooperative post-fusion = -89 us. Do NOT touch structure;
// do NOT raise launch_bounds min (min=5 forced VGPR 48 < 64-reg
// accumulator -> scratch spill, 107->272 us).
__global__ __launch_bounds__(256, 4) void k_energy(
    const unsigned short* __restrict__ Abf, const unsigned short* __restrict__ Wb,
    const float* __restrict__ dech_p, const float* __restrict__ Vv,
    float* __restrict__ part)
{
  __shared__ __align__(16) unsigned short As[128*64];  // 16 KB
  __shared__ __align__(16) unsigned short Bs[128*64];  // 16 KB

  int hw = blockIdx.x;
  int logical = (hw & 7)*512 + (hw >> 3);   // XCD-contiguous (4096 % 8 == 0)
  int mt = logical >> 4, nt = logical & 15; // mt 0..255, nt 0..15
  int b = mt >> 4;
  int trow = (mt & 15)*128;
  int h = nt >> 2;

  const char* Ag = (const char*)(Abf + ((size_t)b*MROWS + trow)*KT);
  const char* Bg = (const char*)(Wb + (size_t)nt*128*KT);

  int tid = threadIdx.x, lane = tid & 63, w = tid >> 6;  // 4 waves
  int wm = w >> 1, wn = w & 1;

  int srow = tid >> 3;                      // 0..31
  size_t scol = (size_t)(((tid & 7) ^ (srow & 7)) * 16);
  int wub = w * 1024;

  int cx0 = (((lane >> 4) * 16)     ) ^ ((lane & 7) << 4);
  int cx1 = (((lane >> 4) * 16) + 64) ^ ((lane & 7) << 4);
  int arow = (wm*64 + (lane & 15)) * 128;
  int brow = (wn*64 + (lane & 15)) * 128;

  float dv[4], vv[4];
  #pragma unroll
  for (int q = 0; q < 4; q++){
    int a = (nt & 3)*128 + wn*64 + q*16 + (lane & 15);
    int bh = b*4 + h;
    dv[q] = dech_p[((size_t)0*64 + bh)*512 + a] + dech_p[((size_t)1*64 + bh)*512 + a]
          + dech_p[((size_t)2*64 + bh)*512 + a] + dech_p[((size_t)3*64 + bh)*512 + a];
    vv[q] = Vv[h*A_ + a];
  }

  f32x4 acc[4][4];
  #pragma unroll
  for (int m = 0; m < 4; m++)
    #pragma unroll
    for (int q = 0; q < 4; q++) acc[m][q] = (f32x4){0.f,0.f,0.f,0.f};

  for (int ks = 0; ks < NKT; ks++){
    __syncthreads();
    #pragma unroll
    for (int j = 0; j < 4; j++){
      gl16(Ag + (size_t)(j*32 + srow)*(KT*2) + (size_t)ks*128 + scol, (char*)As + j*4096 + wub);
      gl16(Bg + (size_t)(j*32 + srow)*(KT*2) + (size_t)ks*128 + scol, (char*)Bs + j*4096 + wub);
    }
    __syncthreads();
    short8 af[2][4], bf[2][4];
    #pragma unroll
    for (int m = 0; m < 4; m++){
      af[0][m] = *(const short8*)((const char*)As + arow + m*2048 + cx0);
      af[1][m] = *(const short8*)((const char*)As + arow + m*2048 + cx1);
    }
    #pragma unroll
    for (int q = 0; q < 4; q++){
      bf[0][q] = *(const short8*)((const char*)Bs + brow + q*2048 + cx0);
      bf[1][q] = *(const short8*)((const char*)Bs + brow + q*2048 + cx1);
    }
    #pragma unroll
    for (int kk = 0; kk < 2; kk++)
      #pragma unroll
      for (int q = 0; q < 4; q++)
        #pragma unroll
        for (int m = 0; m < 4; m++)
          acc[m][q] = __builtin_amdgcn_mfma_f32_16x16x32_bf16(af[kk][m], bf[kk][q], acc[m][q], 0, 0, 0);
  }

  // epilogue: tanh+V reduce -> ered[wn][tl] (single writer per slot), then
  // wn-merge and one coalesced 128x4B store per block.
  __syncthreads();                    // all LDS reads retired; reuse As
  float* ered = (float*)As;           // [2][128]
  #pragma unroll
  for (int m = 0; m < 4; m++){
    #pragma unroll
    for (int r = 0; r < 4; r++){
      float ps = 0.f;
      #pragma unroll
      for (int q = 0; q < 4; q++)
        ps = fmaf(pade_tanh(acc[m][q][r] + dv[q]), vv[q], ps);
      ROW16_SUM(ps);
      if ((lane & 15) == 0)
        ered[wn*128 + wm*64 + m*16 + (lane >> 4)*4 + r] = ps;
    }
  }
  __syncthreads();
  if (tid < 128){
    int t = trow + tid;
    if (t < T_)
      part[(((size_t)(nt & 3)*16 + b)*H_ + h)*TP + t] = ered[tid] + ered[128 + tid];
  }
}

// ---------------------------------------------------------------------------
// softmax over T per (b,h); sums 4 coalesced partial slices, applies mask
__global__ void k_softmax(const float* __restrict__ part, const int* __restrict__ x_lens,
                          float* __restrict__ aw){
  int h = blockIdx.x, b = blockIdx.y;
  __shared__ float sh[T_];
  __shared__ float red[8];
  int tid = threadIdx.x;
  int xl = x_lens[b];
  float mx = -1e30f;
  for (int t = tid; t < T_; t += 256){
    float e = 0.f;
    if (t < xl){
      e = part[(((size_t)0*16 + b)*H_ + h)*TP + t]
        + part[(((size_t)1*16 + b)*H_ + h)*TP + t]
        + part[(((size_t)2*16 + b)*H_ + h)*TP + t]
        + part[(((size_t)3*16 + b)*H_ + h)*TP + t];
    }
    sh[t] = e;
    mx = fmaxf(mx, e);
  }
  #pragma unroll
  for (int o = 32; o; o >>= 1) mx = fmaxf(mx, __shfl_xor(mx, o));
  if ((tid & 63) == 0) red[tid >> 6] = mx;
  __syncthreads();
  mx = fmaxf(fmaxf(red[0], red[1]), fmaxf(red[2], red[3]));
  float sm = 0.f;
  for (int t = tid; t < T_; t += 256){
    float ex = __expf(sh[t] - mx);
    sh[t] = ex;
    sm += ex;
  }
  #pragma unroll
  for (int o = 32; o; o >>= 1) sm += __shfl_xor(sm, o);
  if ((tid & 63) == 0) red[4 + (tid >> 6)] = sm;
  __syncthreads();
  sm = red[4] + red[5] + red[6] + red[7];
  float inv = 1.f / sm;
  for (int t = tid; t < T_; t += 256){
    aw[((size_t)b*T_ + t)*H_ + h] = sh[t] * inv;
  }
}

// ---------------------------------------------------------------------------
// partial context from bf16 Abf
#define CCH 125
__global__ void k_ctxp(const unsigned short* __restrict__ Abf, const float* __restrict__ aw,
                       float* __restrict__ ctxp){
  int ch = blockIdx.x, b = blockIdx.y;
  int t0 = ch * CCH;
  __shared__ float awl[CCH * 4];
  int tid = threadIdx.x;
  for (int i = tid; i < CCH*4; i += 256)
    awl[i] = aw[((size_t)b*T_ + t0)*H_ + i];
  __syncthreads();
  int e0 = tid * 2;
  float a0x=0,a0y=0,a1x=0,a1y=0,a2x=0,a2y=0,a3x=0,a3y=0;
  #pragma unroll 5
  for (int tl = 0; tl < CCH; tl++){
    uint uv = *(const uint*)&Abf[((size_t)b*MROWS + t0 + tl)*KT + e0];
    float evx = __uint_as_float(uv << 16);
    float evy = __uint_as_float(uv & 0xFFFF0000u);
    float w0 = awl[tl*4+0], w1 = awl[tl*4+1], w2 = awl[tl*4+2], w3 = awl[tl*4+3];
    a0x = fmaf(w0, evx, a0x); a0y = fmaf(w0, evy, a0y);
    a1x = fmaf(w1, evx, a1x); a1y = fmaf(w1, evy, a1y);
    a2x = fmaf(w2, evx, a2x); a2y = fmaf(w2, evy, a2y);
    a3x = fmaf(w3, evx, a3x); a3y = fmaf(w3, evy, a3y);
  }
  size_t base = ((size_t)(b*16) + ch) * (H_*E_);
  ctxp[base + 0*E_ + e0] = a0x; ctxp[base + 0*E_ + e0+1] = a0y;
  ctxp[base + 1*E_ + e0] = a1x; ctxp[base + 1*E_ + e0+1] = a1y;
  ctxp[base + 2*E_ + e0] = a2x; ctxp[base + 2*E_ + e0+1] = a2y;
  ctxp[base + 3*E_ + e0] = a3x; ctxp[base + 3*E_ + e0+1] = a3y;
}

// ---------------------------------------------------------------------------
// final GEMM: fpart[kq][b][eo] over he-slice; ch-sum of ctxp inlined in loader.
// grid (32 kq, 8 g); block computes 16 b x 64 eo. Wm read exactly once.
__global__ void k_fgemm(const float* __restrict__ ctxp, const float* __restrict__ Wm,
                        float* __restrict__ fpart){
  int kq = blockIdx.x, g = blockIdx.y;
  __shared__ float cpl[16][64];
  __shared__ float red[4][16][64];
  int tid = threadIdx.x;
  { // load + ch-reduce cpa slice: thread -> (b = tid>>4, i4 = (tid&15)*4)
    int b = tid >> 4, i4 = (tid & 15) * 4;
    const float* base = ctxp + (size_t)b*16*2048 + kq*64 + i4;
    float sx = 0.f, sy = 0.f, sz = 0.f, sw = 0.f;
    #pragma unroll
    for (int ch = 0; ch < 16; ch++){
      float4 v = *(const float4*)(base + (size_t)ch*2048);
      sx += v.x; sy += v.y; sz += v.z; sw += v.w;
    }
    cpl[b][i4] = sx; cpl[b][i4+1] = sy; cpl[b][i4+2] = sz; cpl[b][i4+3] = sw;
  }
  __syncthreads();
  int e = tid & 63, p = tid >> 6;
  float acc[16];
  #pragma unroll
  for (int b = 0; b < 16; b++) acc[b] = 0.f;
  #pragma unroll
  for (int i = 0; i < 16; i++){
    int he = kq*64 + p*16 + i;
    float wv = Wm[(size_t)he*512 + g*64 + e];
    #pragma unroll
    for (int b = 0; b < 16; b++)
      acc[b] = fmaf(cpl[b][p*16 + i], wv, acc[b]);
  }
  #pragma unroll
  for (int b = 0; b < 16; b++) red[p][b][e] = acc[b];
  __syncthreads();
  int bq = tid >> 6;          // 0..3
  #pragma unroll
  for (int j = 0; j < 4; j++){
    int b = bq*4 + j;
    float s = red[0][b][e] + red[1][b][e] + red[2][b][e] + red[3][b][e];
    fpart[(((size_t)kq*16) + b)*512 + g*64 + e] = s;
  }
}

// ---------------------------------------------------------------------------
// final reduce: out[b][eo] = bm[eo] + sum_kq fpart[kq][b][eo]; grid (16,2)
__global__ void k_fred(const float* __restrict__ fpart, const float* __restrict__ bm,
                       float* __restrict__ out){
  int b = blockIdx.x, qq = blockIdx.y, tid = threadIdx.x;
  int eo = qq*256 + tid;
  float acc = bm[eo];
  #pragma unroll 8
  for (int kq = 0; kq < 32; kq++)
    acc += fpart[(((size_t)kq*16) + b)*512 + eo];
  out[(size_t)b*512 + eo] = acc;
}

// ---------------------------------------------------------------------------
extern "C" void kernel_launch(void* const* d_in, const int* in_sizes, int n_in,
                              void* d_out, int out_size, void* d_ws, size_t ws_size,
                              hipStream_t stream){
  const float* enc    = (const float*)d_in[0];
  const int*   xl     = (const int*)  d_in[1];
  const float* dec    = (const float*)d_in[2];
  const float* awstep = (const float*)d_in[3];
  const float* We     = (const float*)d_in[4];
  const float* be     = (const float*)d_in[5];
  const float* Wd     = (const float*)d_in[6];
  const float* Wc     = (const float*)d_in[7];
  const float* convw  = (const float*)d_in[8];
  const float* Vv     = (const float*)d_in[9];
  const float* Wm     = (const float*)d_in[10];
  const float* bm     = (const float*)d_in[11];

  float* out_ctx = (float*)d_out;
  float* out_aw  = (float*)d_out + (size_t)B_ * E_;

  char* ws = (char*)d_ws;
  unsigned short* Wcomb = (unsigned short*)ws; ws += (size_t)2048*KT*2;        //  2,359,296
  unsigned short* Abf   = (unsigned short*)ws; ws += (size_t)B_*MROWS*KT*2;    // 37,748,736
  float* dech_p    = (float*)ws; ws += (size_t)4*64*512*4;                     //    524,288
  float* part      = (float*)ws; ws += (size_t)4*B_*H_*TP*4;                   //  2,097,152
  float* ctxp      = (float*)ws; ws += (size_t)B_*16*H_*E_*4;                  //  2,097,152
  float* fpart     = (float*)ws; ws += (size_t)32*B_*512*4;                    //  1,048,576

  k_pre    <<<dim3(3968),    dim3(256), 0, stream>>>(awstep, convw, We, Wc, Wcomb,
                                                     dec, Wd, be, dech_p, enc, Abf);
  k_energy <<<dim3(4096),    dim3(256), 0, stream>>>(Abf, Wcomb, dech_p, Vv, part);
  k_softmax<<<dim3(H_, B_),  dim3(256), 0, stream>>>(part, xl, out_aw);
  k_ctxp   <<<dim3(16, B_),  dim3(256), 0, stream>>>(Abf, out_aw, ctxp);
  k_fgemm  <<<dim3(32, 8),   dim3(256), 0, stream>>>(ctxp, Wm, fpart);
  k_fred   <<<dim3(B_, 2),   dim3(256), 0, stream>>>(fpart, bm, out_ctx);
}

// Round 15
// 129.085 us; speedup vs baseline: 1.9567x; 1.2621x over previous
//
#include <hip/hip_runtime.h>

typedef __attribute__((ext_vector_type(8))) short short8;
typedef __attribute__((ext_vector_type(4))) float f32x4;

#define B_ 16
#define T_ 2000
#define E_ 512
#define A_ 512
#define H_ 4
#define C_ 10
#define KW_ 201
#define KT 576      // 512 enc + 40 conv (4 heads x 10) + 24 zero pad
#define MROWS 2048  // padded T per batch
#define NKT 9       // 576 / 64 K-tiles
#define TP 2048     // padded T for part

__device__ __forceinline__ unsigned short f2bf(float f){
  unsigned int u = __float_as_uint(f);
  u += 0x7FFFu + ((u >> 16) & 1u);   // round-to-nearest-even
  return (unsigned short)(u >> 16);
}
// Pade tanh + clamp; |err|<1e-5 for |x|<2; args here are ~N(0,0.65).
__device__ __forceinline__ float pade_tanh(float x){
  float t = x * x;
  float n = x * fmaf(t, t + 105.f, 945.f);
  float d = fmaf(t, fmaf(t, 15.f, 420.f), 945.f);
  float r = __fdividef(n, d);
  return fminf(1.f, fmaxf(-1.f, r));
}
__device__ __forceinline__ void gl16(const void* g, void* lds){
  __builtin_amdgcn_global_load_lds((const __attribute__((address_space(1))) void*)g,
                                   (__attribute__((address_space(3))) void*)lds, 16, 0, 0);
}
#define DPP_ADD(x, ctrl) do { \
  int _y = __builtin_amdgcn_mov_dpp(__float_as_int(x), (ctrl), 0xf, 0xf, true); \
  (x) += __int_as_float(_y); } while(0)
#define ROW16_SUM(x) do { DPP_ADD(x,0xB1); DPP_ADD(x,0x4E); DPP_ADD(x,0x124); DPP_ADD(x,0x128); } while(0)

// ---------------------------------------------------------------------------
// Fat preprocessing kernel, one launch, disjoint writes:
//   [0,2048)    enc-pack: Abf cols 0..511 (bf16) + zero cols 552..575 (+ full-zero rows >= 2000)
//   [2048,2560) conv: Abf cols 512..551 directly (bf16); chunks with t0 >= x_lens[b]
//               are dead (consumed only by k_energy blocks that early-exit) -> skip
//   [2560,3712) wcomb transpose-pack
//   [3712,3968) dec partials
#define TCH 250
__global__ void k_pre(const float* __restrict__ aw_step, const float* __restrict__ conv_w,
                      const float* __restrict__ We, const float* __restrict__ Wc,
                      unsigned short* __restrict__ Wcomb,
                      const float* __restrict__ dec, const float* __restrict__ Wd,
                      const float* __restrict__ be, float* __restrict__ dech_p,
                      const float* __restrict__ enc, unsigned short* __restrict__ Abf,
                      const int* __restrict__ x_lens){
  __shared__ float pool[2460];
  int bid = blockIdx.x, tid = threadIdx.x;
  if (bid < 2048){
    // ---- enc-pack (cannot skip: k_ctxp reads cols 0..511 for ALL t)
    int b = bid >> 7, r0 = (bid & 127) * 16;
    if (r0 < 2000){
      for (int idx = tid; idx < 16*134; idx += 256){
        int row = idx / 134, g = idx % 134;
        if (g >= 128) g += 10;               // zero-tail cols 552..575
        int t = r0 + row;
        float4 v = make_float4(0.f,0.f,0.f,0.f);
        if (g < 128) v = *(const float4*)&enc[((size_t)b*T_ + t)*E_ + g*4];
        ushort4 u; u.x = f2bf(v.x); u.y = f2bf(v.y); u.z = f2bf(v.z); u.w = f2bf(v.w);
        *(ushort4*)&Abf[((size_t)b*MROWS + t)*KT + g*4] = u;
      }
    } else {
      ushort4 z = {0,0,0,0};
      for (int idx = tid; idx < 16*144; idx += 256){
        int row = idx / 144, g = idx % 144;
        *(ushort4*)&Abf[((size_t)b*MROWS + r0 + row)*KT + g*4] = z;
      }
    }
  } else if (bid < 2560){
    // ---- conv: register sliding window, thread owns 10 t for one channel;
    //      writes bf16 features straight into Abf cols 512..551
    int j = bid - 2048;
    int tc = j & 7, h = (j >> 3) & 3, b = j >> 5;
    int t0 = tc * TCH;
    if (t0 >= x_lens[b]) return;     // dead rows: only read by early-exited k_energy blocks
    float* awl = pool;          // [450]
    float* wl  = pool + 450;    // [2010]
    for (int i = tid; i < TCH + 200; i += 256){
      int t = t0 - 100 + i;
      awl[i] = (t >= 0 && t < T_) ? aw_step[((size_t)b*T_ + t)*H_ + h] : 0.f;
    }
    for (int i = tid; i < C_*KW_; i += 256)
      wl[i] = conv_w[(size_t)h*C_*KW_ + i];
    __syncthreads();
    int c = tid % 10, g = tid / 10;
    bool act = g < 25;
    int tb = act ? g * 10 : 0;
    const float* wc = &wl[c * KW_];
    float acc[10], win[10];
    #pragma unroll
    for (int jj = 0; jj < 10; jj++){ acc[jj] = 0.f; win[jj] = awl[tb + jj]; }
    for (int k0 = 0; k0 < 200; k0 += 10){
      #pragma unroll
      for (int u = 0; u < 10; u++){
        float wk = wc[k0 + u];
        #pragma unroll
        for (int jj = 0; jj < 10; jj++)
          acc[jj] = fmaf(win[(jj + u) % 10], wk, acc[jj]);
        win[u] = awl[tb + k0 + u + 10];
      }
    }
    float wk = wc[200];
    #pragma unroll
    for (int jj = 0; jj < 10; jj++)
      acc[jj] = fmaf(win[jj], wk, acc[jj]);
    if (act){
      #pragma unroll
      for (int jj = 0; jj < 10; jj++)
        Abf[((size_t)b*MROWS + t0 + tb + jj)*KT + 512 + h*C_ + c] = f2bf(acc[jj]);
    }
  } else if (bid < 3712){
    // ---- wcomb: Wcomb[n=h*512+a][k] transpose-pack to bf16
    int j = bid - 2560;
    int k0 = (j % 18) * 32, n0 = (j / 18) * 32;
    int h = n0 >> 9, a0 = n0 & 511;
    float (*tt)[33] = (float(*)[33])pool;
    int tx = tid & 31, ty = tid >> 5;   // 32 x 8
    for (int i = ty; i < 32; i += 8){
      int k = k0 + i;
      float v = 0.f;
      if (k < 512) {
        v = We[((size_t)(h*512) + k)*512 + a0 + tx];
      } else if (k < 552) {
        int jj = k - 512, hp = jj / 10, c = jj % 10;
        if (hp == h) v = Wc[(size_t)(h*10 + c)*512 + a0 + tx];
      }
      tt[i][tx] = v;
    }
    __syncthreads();
    for (int i = ty; i < 32; i += 8)
      Wcomb[((size_t)n0 + i)*KT + k0 + tx] = f2bf(tt[tx][i]);
  } else {
    // ---- dec partials: dech_p[dq][b*4+h][a]
    int j = bid - 3712;
    int bh = j & 63, dq = j >> 6;
    int a0 = tid * 2;
    int h = bh & 3;
    float acc0 = 0.f, acc1 = 0.f;
    if (dq == 0){ acc0 = be[h*512 + a0]; acc1 = be[h*512 + a0 + 1]; }
    const float* w = Wd + (size_t)h*512*512 + (size_t)dq*128*512;
    const float* dv = dec + (bh >> 2)*512 + dq*128;
    #pragma unroll 4
    for (int d = 0; d < 128; d++){
      float x = dv[d];
      acc0 = fmaf(x, w[(size_t)d*512 + a0],     acc0);
      acc1 = fmaf(x, w[(size_t)d*512 + a0 + 1], acc1);
    }
    dech_p[((size_t)dq*64 + bh)*512 + a0]     = acc0;
    dech_p[((size_t)dq*64 + bh)*512 + a0 + 1] = acc1;
  }
}

// ---------------------------------------------------------------------------
// 128x128 swizzled TLP GEMM — PINNED ENGINE (round-10 validated: 105 us,
// MfmaUtil 32%, VGPR 64). Round-5/11/13 A/Bs: 8-phase sched = null, 256-row
// tile = -9%, cooperative post-fusion = -89 us. Do NOT touch structure;
// do NOT raise launch_bounds min (min=5 forced VGPR 48 < 64-reg
// accumulator -> scratch spill, 107->272 us).
// NEW: early-exit for trow >= x_lens[b] — reference masks energy to 0 there
// (k_softmax substitutes 0 and never reads those partials), so whole blocks
// above xl are provably dead work. Block-uniform branch, barrier-safe.
__global__ __launch_bounds__(256, 4) void k_energy(
    const unsigned short* __restrict__ Abf, const unsigned short* __restrict__ Wb,
    const float* __restrict__ dech_p, const float* __restrict__ Vv,
    const int* __restrict__ x_lens, float* __restrict__ part)
{
  __shared__ __align__(16) unsigned short As[128*64];  // 16 KB
  __shared__ __align__(16) unsigned short Bs[128*64];  // 16 KB

  int hw = blockIdx.x;
  int logical = (hw & 7)*512 + (hw >> 3);   // XCD-contiguous (4096 % 8 == 0)
  int mt = logical >> 4, nt = logical & 15; // mt 0..255, nt 0..15
  int b = mt >> 4;
  int trow = (mt & 15)*128;
  int h = nt >> 2;

  int xl = x_lens[b];
  if (trow >= xl) return;                   // dead rows: energy masked to 0

  const char* Ag = (const char*)(Abf + ((size_t)b*MROWS + trow)*KT);
  const char* Bg = (const char*)(Wb + (size_t)nt*128*KT);

  int tid = threadIdx.x, lane = tid & 63, w = tid >> 6;  // 4 waves
  int wm = w >> 1, wn = w & 1;

  int srow = tid >> 3;                      // 0..31
  size_t scol = (size_t)(((tid & 7) ^ (srow & 7)) * 16);
  int wub = w * 1024;

  int cx0 = (((lane >> 4) * 16)     ) ^ ((lane & 7) << 4);
  int cx1 = (((lane >> 4) * 16) + 64) ^ ((lane & 7) << 4);
  int arow = (wm*64 + (lane & 15)) * 128;
  int brow = (wn*64 + (lane & 15)) * 128;

  float dv[4], vv[4];
  #pragma unroll
  for (int q = 0; q < 4; q++){
    int a = (nt & 3)*128 + wn*64 + q*16 + (lane & 15);
    int bh = b*4 + h;
    dv[q] = dech_p[((size_t)0*64 + bh)*512 + a] + dech_p[((size_t)1*64 + bh)*512 + a]
          + dech_p[((size_t)2*64 + bh)*512 + a] + dech_p[((size_t)3*64 + bh)*512 + a];
    vv[q] = Vv[h*A_ + a];
  }

  f32x4 acc[4][4];
  #pragma unroll
  for (int m = 0; m < 4; m++)
    #pragma unroll
    for (int q = 0; q < 4; q++) acc[m][q] = (f32x4){0.f,0.f,0.f,0.f};

  for (int ks = 0; ks < NKT; ks++){
    __syncthreads();
    #pragma unroll
    for (int j = 0; j < 4; j++){
      gl16(Ag + (size_t)(j*32 + srow)*(KT*2) + (size_t)ks*128 + scol, (char*)As + j*4096 + wub);
      gl16(Bg + (size_t)(j*32 + srow)*(KT*2) + (size_t)ks*128 + scol, (char*)Bs + j*4096 + wub);
    }
    __syncthreads();
    short8 af[2][4], bf[2][4];
    #pragma unroll
    for (int m = 0; m < 4; m++){
      af[0][m] = *(const short8*)((const char*)As + arow + m*2048 + cx0);
      af[1][m] = *(const short8*)((const char*)As + arow + m*2048 + cx1);
    }
    #pragma unroll
    for (int q = 0; q < 4; q++){
      bf[0][q] = *(const short8*)((const char*)Bs + brow + q*2048 + cx0);
      bf[1][q] = *(const short8*)((const char*)Bs + brow + q*2048 + cx1);
    }
    #pragma unroll
    for (int kk = 0; kk < 2; kk++)
      #pragma unroll
      for (int q = 0; q < 4; q++)
        #pragma unroll
        for (int m = 0; m < 4; m++)
          acc[m][q] = __builtin_amdgcn_mfma_f32_16x16x32_bf16(af[kk][m], bf[kk][q], acc[m][q], 0, 0, 0);
  }

  // epilogue: tanh+V reduce -> ered[wn][tl] (single writer per slot), then
  // wn-merge and one coalesced 128x4B store per block.
  __syncthreads();                    // all LDS reads retired; reuse As
  float* ered = (float*)As;           // [2][128]
  #pragma unroll
  for (int m = 0; m < 4; m++){
    #pragma unroll
    for (int r = 0; r < 4; r++){
      float ps = 0.f;
      #pragma unroll
      for (int q = 0; q < 4; q++)
        ps = fmaf(pade_tanh(acc[m][q][r] + dv[q]), vv[q], ps);
      ROW16_SUM(ps);
      if ((lane & 15) == 0)
        ered[wn*128 + wm*64 + m*16 + (lane >> 4)*4 + r] = ps;
    }
  }
  __syncthreads();
  if (tid < 128){
    int t = trow + tid;
    if (t < T_)
      part[(((size_t)(nt & 3)*16 + b)*H_ + h)*TP + t] = ered[tid] + ered[128 + tid];
  }
}

// ---------------------------------------------------------------------------
// softmax over T per (b,h); sums 4 coalesced partial slices, applies mask
__global__ void k_softmax(const float* __restrict__ part, const int* __restrict__ x_lens,
                          float* __restrict__ aw){
  int h = blockIdx.x, b = blockIdx.y;
  __shared__ float sh[T_];
  __shared__ float red[8];
  int tid = threadIdx.x;
  int xl = x_lens[b];
  float mx = -1e30f;
  for (int t = tid; t < T_; t += 256){
    float e = 0.f;
    if (t < xl){
      e = part[(((size_t)0*16 + b)*H_ + h)*TP + t]
        + part[(((size_t)1*16 + b)*H_ + h)*TP + t]
        + part[(((size_t)2*16 + b)*H_ + h)*TP + t]
        + part[(((size_t)3*16 + b)*H_ + h)*TP + t];
    }
    sh[t] = e;
    mx = fmaxf(mx, e);
  }
  #pragma unroll
  for (int o = 32; o; o >>= 1) mx = fmaxf(mx, __shfl_xor(mx, o));
  if ((tid & 63) == 0) red[tid >> 6] = mx;
  __syncthreads();
  mx = fmaxf(fmaxf(red[0], red[1]), fmaxf(red[2], red[3]));
  float sm = 0.f;
  for (int t = tid; t < T_; t += 256){
    float ex = __expf(sh[t] - mx);
    sh[t] = ex;
    sm += ex;
  }
  #pragma unroll
  for (int o = 32; o; o >>= 1) sm += __shfl_xor(sm, o);
  if ((tid & 63) == 0) red[4 + (tid >> 6)] = sm;
  __syncthreads();
  sm = red[4] + red[5] + red[6] + red[7];
  float inv = 1.f / sm;
  for (int t = tid; t < T_; t += 256){
    aw[((size_t)b*T_ + t)*H_ + h] = sh[t] * inv;
  }
}

// ---------------------------------------------------------------------------
// partial context from bf16 Abf
#define CCH 125
__global__ void k_ctxp(const unsigned short* __restrict__ Abf, const float* __restrict__ aw,
                       float* __restrict__ ctxp){
  int ch = blockIdx.x, b = blockIdx.y;
  int t0 = ch * CCH;
  __shared__ float awl[CCH * 4];
  int tid = threadIdx.x;
  for (int i = tid; i < CCH*4; i += 256)
    awl[i] = aw[((size_t)b*T_ + t0)*H_ + i];
  __syncthreads();
  int e0 = tid * 2;
  float a0x=0,a0y=0,a1x=0,a1y=0,a2x=0,a2y=0,a3x=0,a3y=0;
  #pragma unroll 5
  for (int tl = 0; tl < CCH; tl++){
    uint uv = *(const uint*)&Abf[((size_t)b*MROWS + t0 + tl)*KT + e0];
    float evx = __uint_as_float(uv << 16);
    float evy = __uint_as_float(uv & 0xFFFF0000u);
    float w0 = awl[tl*4+0], w1 = awl[tl*4+1], w2 = awl[tl*4+2], w3 = awl[tl*4+3];
    a0x = fmaf(w0, evx, a0x); a0y = fmaf(w0, evy, a0y);
    a1x = fmaf(w1, evx, a1x); a1y = fmaf(w1, evy, a1y);
    a2x = fmaf(w2, evx, a2x); a2y = fmaf(w2, evy, a2y);
    a3x = fmaf(w3, evx, a3x); a3y = fmaf(w3, evy, a3y);
  }
  size_t base = ((size_t)(b*16) + ch) * (H_*E_);
  ctxp[base + 0*E_ + e0] = a0x; ctxp[base + 0*E_ + e0+1] = a0y;
  ctxp[base + 1*E_ + e0] = a1x; ctxp[base + 1*E_ + e0+1] = a1y;
  ctxp[base + 2*E_ + e0] = a2x; ctxp[base + 2*E_ + e0+1] = a2y;
  ctxp[base + 3*E_ + e0] = a3x; ctxp[base + 3*E_ + e0+1] = a3y;
}

// ---------------------------------------------------------------------------
// final GEMM: fpart[kq][b][eo] over he-slice; ch-sum of ctxp inlined in loader.
// grid (32 kq, 8 g); block computes 16 b x 64 eo. Wm read exactly once.
__global__ void k_fgemm(const float* __restrict__ ctxp, const float* __restrict__ Wm,
                        float* __restrict__ fpart){
  int kq = blockIdx.x, g = blockIdx.y;
  __shared__ float cpl[16][64];
  __shared__ float red[4][16][64];
  int tid = threadIdx.x;
  { // load + ch-reduce cpa slice: thread -> (b = tid>>4, i4 = (tid&15)*4)
    int b = tid >> 4, i4 = (tid & 15) * 4;
    const float* base = ctxp + (size_t)b*16*2048 + kq*64 + i4;
    float sx = 0.f, sy = 0.f, sz = 0.f, sw = 0.f;
    #pragma unroll
    for (int ch = 0; ch < 16; ch++){
      float4 v = *(const float4*)(base + (size_t)ch*2048);
      sx += v.x; sy += v.y; sz += v.z; sw += v.w;
    }
    cpl[b][i4] = sx; cpl[b][i4+1] = sy; cpl[b][i4+2] = sz; cpl[b][i4+3] = sw;
  }
  __syncthreads();
  int e = tid & 63, p = tid >> 6;
  float acc[16];
  #pragma unroll
  for (int b = 0; b < 16; b++) acc[b] = 0.f;
  #pragma unroll
  for (int i = 0; i < 16; i++){
    int he = kq*64 + p*16 + i;
    float wv = Wm[(size_t)he*512 + g*64 + e];
    #pragma unroll
    for (int b = 0; b < 16; b++)
      acc[b] = fmaf(cpl[b][p*16 + i], wv, acc[b]);
  }
  #pragma unroll
  for (int b = 0; b < 16; b++) red[p][b][e] = acc[b];
  __syncthreads();
  int bq = tid >> 6;          // 0..3
  #pragma unroll
  for (int j = 0; j < 4; j++){
    int b = bq*4 + j;
    float s = red[0][b][e] + red[1][b][e] + red[2][b][e] + red[3][b][e];
    fpart[(((size_t)kq*16) + b)*512 + g*64 + e] = s;
  }
}

// ---------------------------------------------------------------------------
// final reduce: out[b][eo] = bm[eo] + sum_kq fpart[kq][b][eo]; grid (16,2)
__global__ void k_fred(const float* __restrict__ fpart, const float* __restrict__ bm,
                       float* __restrict__ out){
  int b = blockIdx.x, qq = blockIdx.y, tid = threadIdx.x;
  int eo = qq*256 + tid;
  float acc = bm[eo];
  #pragma unroll 8
  for (int kq = 0; kq < 32; kq++)
    acc += fpart[(((size_t)kq*16) + b)*512 + eo];
  out[(size_t)b*512 + eo] = acc;
}

// ---------------------------------------------------------------------------
extern "C" void kernel_launch(void* const* d_in, const int* in_sizes, int n_in,
                              void* d_out, int out_size, void* d_ws, size_t ws_size,
                              hipStream_t stream){
  const float* enc    = (const float*)d_in[0];
  const int*   xl     = (const int*)  d_in[1];
  const float* dec    = (const float*)d_in[2];
  const float* awstep = (const float*)d_in[3];
  const float* We     = (const float*)d_in[4];
  const float* be     = (const float*)d_in[5];
  const float* Wd     = (const float*)d_in[6];
  const float* Wc     = (const float*)d_in[7];
  const float* convw  = (const float*)d_in[8];
  const float* Vv     = (const float*)d_in[9];
  const float* Wm     = (const float*)d_in[10];
  const float* bm     = (const float*)d_in[11];

  float* out_ctx = (float*)d_out;
  float* out_aw  = (float*)d_out + (size_t)B_ * E_;

  char* ws = (char*)d_ws;
  unsigned short* Wcomb = (unsigned short*)ws; ws += (size_t)2048*KT*2;        //  2,359,296
  unsigned short* Abf   = (unsigned short*)ws; ws += (size_t)B_*MROWS*KT*2;    // 37,748,736
  float* dech_p    = (float*)ws; ws += (size_t)4*64*512*4;                     //    524,288
  float* part      = (float*)ws; ws += (size_t)4*B_*H_*TP*4;                   //  2,097,152
  float* ctxp      = (float*)ws; ws += (size_t)B_*16*H_*E_*4;                  //  2,097,152
  float* fpart     = (float*)ws; ws += (size_t)32*B_*512*4;                    //  1,048,576

  k_pre    <<<dim3(3968),    dim3(256), 0, stream>>>(awstep, convw, We, Wc, Wcomb,
                                                     dec, Wd, be, dech_p, enc, Abf, xl);
  k_energy <<<dim3(4096),    dim3(256), 0, stream>>>(Abf, Wcomb, dech_p, Vv, xl, part);
  k_softmax<<<dim3(H_, B_),  dim3(256), 0, stream>>>(part, xl, out_aw);
  k_ctxp   <<<dim3(16, B_),  dim3(256), 0, stream>>>(Abf, out_aw, ctxp);
  k_fgemm  <<<dim3(32, 8),   dim3(256), 0, stream>>>(ctxp, Wm, fpart);
  k_fred   <<<dim3(B_, 2),   dim3(256), 0, stream>>>(fpart, bm, out_ctx);
}

// Round 16
// 127.541 us; speedup vs baseline: 1.9804x; 1.0121x over previous
//
#include <hip/hip_runtime.h>

typedef __attribute__((ext_vector_type(8))) short short8;
typedef __attribute__((ext_vector_type(4))) float f32x4;

#define B_ 16
#define T_ 2000
#define E_ 512
#define A_ 512
#define H_ 4
#define C_ 10
#define KW_ 201
#define KT 576      // 512 enc + 40 conv (4 heads x 10) + 24 zero pad
#define MROWS 2048  // padded T per batch
#define NKT 9       // 576 / 64 K-tiles
#define TP 2048     // padded T for part

__device__ __forceinline__ unsigned short f2bf(float f){
  unsigned int u = __float_as_uint(f);
  u += 0x7FFFu + ((u >> 16) & 1u);   // round-to-nearest-even
  return (unsigned short)(u >> 16);
}
// Pade tanh + clamp; |err|<1e-5 for |x|<2; args here are ~N(0,0.65).
__device__ __forceinline__ float pade_tanh(float x){
  float t = x * x;
  float n = x * fmaf(t, t + 105.f, 945.f);
  float d = fmaf(t, fmaf(t, 15.f, 420.f), 945.f);
  float r = __fdividef(n, d);
  return fminf(1.f, fmaxf(-1.f, r));
}
__device__ __forceinline__ void gl16(const void* g, void* lds){
  __builtin_amdgcn_global_load_lds((const __attribute__((address_space(1))) void*)g,
                                   (__attribute__((address_space(3))) void*)lds, 16, 0, 0);
}
#define DPP_ADD(x, ctrl) do { \
  int _y = __builtin_amdgcn_mov_dpp(__float_as_int(x), (ctrl), 0xf, 0xf, true); \
  (x) += __int_as_float(_y); } while(0)
#define ROW16_SUM(x) do { DPP_ADD(x,0xB1); DPP_ADD(x,0x4E); DPP_ADD(x,0x124); DPP_ADD(x,0x128); } while(0)

// ---------------------------------------------------------------------------
// Fat preprocessing kernel, one launch, disjoint writes:
//   [0,2048)    enc-pack: Abf cols 0..511 (bf16) + zero cols 552..575 (+ full-zero rows >= 2000)
//   [2048,2560) conv: Abf cols 512..551 directly (bf16); chunks with t0 >= x_lens[b]
//               are dead (consumed only by k_energy blocks that early-exit) -> skip
//   [2560,3712) wcomb transpose-pack
//   [3712,3968) dec partials
#define TCH 250
__global__ void k_pre(const float* __restrict__ aw_step, const float* __restrict__ conv_w,
                      const float* __restrict__ We, const float* __restrict__ Wc,
                      unsigned short* __restrict__ Wcomb,
                      const float* __restrict__ dec, const float* __restrict__ Wd,
                      const float* __restrict__ be, float* __restrict__ dech_p,
                      const float* __restrict__ enc, unsigned short* __restrict__ Abf,
                      const int* __restrict__ x_lens){
  __shared__ float pool[2460];
  int bid = blockIdx.x, tid = threadIdx.x;
  if (bid < 2048){
    // ---- enc-pack (cannot skip: k_ctxp reads cols 0..511 for ALL t)
    int b = bid >> 7, r0 = (bid & 127) * 16;
    if (r0 < 2000){
      for (int idx = tid; idx < 16*134; idx += 256){
        int row = idx / 134, g = idx % 134;
        if (g >= 128) g += 10;               // zero-tail cols 552..575
        int t = r0 + row;
        float4 v = make_float4(0.f,0.f,0.f,0.f);
        if (g < 128) v = *(const float4*)&enc[((size_t)b*T_ + t)*E_ + g*4];
        ushort4 u; u.x = f2bf(v.x); u.y = f2bf(v.y); u.z = f2bf(v.z); u.w = f2bf(v.w);
        *(ushort4*)&Abf[((size_t)b*MROWS + t)*KT + g*4] = u;
      }
    } else {
      ushort4 z = {0,0,0,0};
      for (int idx = tid; idx < 16*144; idx += 256){
        int row = idx / 144, g = idx % 144;
        *(ushort4*)&Abf[((size_t)b*MROWS + r0 + row)*KT + g*4] = z;
      }
    }
  } else if (bid < 2560){
    // ---- conv: register sliding window, thread owns 10 t for one channel;
    //      writes bf16 features straight into Abf cols 512..551
    int j = bid - 2048;
    int tc = j & 7, h = (j >> 3) & 3, b = j >> 5;
    int t0 = tc * TCH;
    if (t0 >= x_lens[b]) return;     // dead rows: only read by early-exited k_energy blocks
    float* awl = pool;          // [450]
    float* wl  = pool + 450;    // [2010]
    for (int i = tid; i < TCH + 200; i += 256){
      int t = t0 - 100 + i;
      awl[i] = (t >= 0 && t < T_) ? aw_step[((size_t)b*T_ + t)*H_ + h] : 0.f;
    }
    for (int i = tid; i < C_*KW_; i += 256)
      wl[i] = conv_w[(size_t)h*C_*KW_ + i];
    __syncthreads();
    int c = tid % 10, g = tid / 10;
    bool act = g < 25;
    int tb = act ? g * 10 : 0;
    const float* wc = &wl[c * KW_];
    float acc[10], win[10];
    #pragma unroll
    for (int jj = 0; jj < 10; jj++){ acc[jj] = 0.f; win[jj] = awl[tb + jj]; }
    for (int k0 = 0; k0 < 200; k0 += 10){
      #pragma unroll
      for (int u = 0; u < 10; u++){
        float wk = wc[k0 + u];
        #pragma unroll
        for (int jj = 0; jj < 10; jj++)
          acc[jj] = fmaf(win[(jj + u) % 10], wk, acc[jj]);
        win[u] = awl[tb + k0 + u + 10];
      }
    }
    float wk = wc[200];
    #pragma unroll
    for (int jj = 0; jj < 10; jj++)
      acc[jj] = fmaf(win[jj], wk, acc[jj]);
    if (act){
      #pragma unroll
      for (int jj = 0; jj < 10; jj++)
        Abf[((size_t)b*MROWS + t0 + tb + jj)*KT + 512 + h*C_ + c] = f2bf(acc[jj]);
    }
  } else if (bid < 3712){
    // ---- wcomb: Wcomb[n=h*512+a][k] transpose-pack to bf16
    int j = bid - 2560;
    int k0 = (j % 18) * 32, n0 = (j / 18) * 32;
    int h = n0 >> 9, a0 = n0 & 511;
    float (*tt)[33] = (float(*)[33])pool;
    int tx = tid & 31, ty = tid >> 5;   // 32 x 8
    for (int i = ty; i < 32; i += 8){
      int k = k0 + i;
      float v = 0.f;
      if (k < 512) {
        v = We[((size_t)(h*512) + k)*512 + a0 + tx];
      } else if (k < 552) {
        int jj = k - 512, hp = jj / 10, c = jj % 10;
        if (hp == h) v = Wc[(size_t)(h*10 + c)*512 + a0 + tx];
      }
      tt[i][tx] = v;
    }
    __syncthreads();
    for (int i = ty; i < 32; i += 8)
      Wcomb[((size_t)n0 + i)*KT + k0 + tx] = f2bf(tt[tx][i]);
  } else {
    // ---- dec partials: dech_p[dq][b*4+h][a]
    int j = bid - 3712;
    int bh = j & 63, dq = j >> 6;
    int a0 = tid * 2;
    int h = bh & 3;
    float acc0 = 0.f, acc1 = 0.f;
    if (dq == 0){ acc0 = be[h*512 + a0]; acc1 = be[h*512 + a0 + 1]; }
    const float* w = Wd + (size_t)h*512*512 + (size_t)dq*128*512;
    const float* dv = dec + (bh >> 2)*512 + dq*128;
    #pragma unroll 4
    for (int d = 0; d < 128; d++){
      float x = dv[d];
      acc0 = fmaf(x, w[(size_t)d*512 + a0],     acc0);
      acc1 = fmaf(x, w[(size_t)d*512 + a0 + 1], acc1);
    }
    dech_p[((size_t)dq*64 + bh)*512 + a0]     = acc0;
    dech_p[((size_t)dq*64 + bh)*512 + a0 + 1] = acc1;
  }
}

// ---------------------------------------------------------------------------
// 128x128 swizzled TLP GEMM — PINNED ENGINE (round-10 validated: 105 us,
// MfmaUtil 32%, VGPR 64). Round-5/11/13 A/Bs: 8-phase sched = null, 256-row
// tile = -9%, cooperative post-fusion = -89 us. Do NOT touch structure;
// do NOT raise launch_bounds min (min=5 forced VGPR 48 < 64-reg
// accumulator -> scratch spill, 107->272 us).
// Early-exit for trow >= x_lens[b] (round-15: 105 -> 72 us); part stores
// masked to t < xl (rows >= xl never read by k_softmax).
__global__ __launch_bounds__(256, 4) void k_energy(
    const unsigned short* __restrict__ Abf, const unsigned short* __restrict__ Wb,
    const float* __restrict__ dech_p, const float* __restrict__ Vv,
    const int* __restrict__ x_lens, float* __restrict__ part)
{
  __shared__ __align__(16) unsigned short As[128*64];  // 16 KB
  __shared__ __align__(16) unsigned short Bs[128*64];  // 16 KB

  int hw = blockIdx.x;
  int logical = (hw & 7)*512 + (hw >> 3);   // XCD-contiguous (4096 % 8 == 0)
  int mt = logical >> 4, nt = logical & 15; // mt 0..255, nt 0..15
  int b = mt >> 4;
  int trow = (mt & 15)*128;
  int h = nt >> 2;

  int xl = x_lens[b];
  if (trow >= xl) return;                   // dead rows: energy masked to 0

  const char* Ag = (const char*)(Abf + ((size_t)b*MROWS + trow)*KT);
  const char* Bg = (const char*)(Wb + (size_t)nt*128*KT);

  int tid = threadIdx.x, lane = tid & 63, w = tid >> 6;  // 4 waves
  int wm = w >> 1, wn = w & 1;

  int srow = tid >> 3;                      // 0..31
  size_t scol = (size_t)(((tid & 7) ^ (srow & 7)) * 16);
  int wub = w * 1024;

  int cx0 = (((lane >> 4) * 16)     ) ^ ((lane & 7) << 4);
  int cx1 = (((lane >> 4) * 16) + 64) ^ ((lane & 7) << 4);
  int arow = (wm*64 + (lane & 15)) * 128;
  int brow = (wn*64 + (lane & 15)) * 128;

  float dv[4], vv[4];
  #pragma unroll
  for (int q = 0; q < 4; q++){
    int a = (nt & 3)*128 + wn*64 + q*16 + (lane & 15);
    int bh = b*4 + h;
    dv[q] = dech_p[((size_t)0*64 + bh)*512 + a] + dech_p[((size_t)1*64 + bh)*512 + a]
          + dech_p[((size_t)2*64 + bh)*512 + a] + dech_p[((size_t)3*64 + bh)*512 + a];
    vv[q] = Vv[h*A_ + a];
  }

  f32x4 acc[4][4];
  #pragma unroll
  for (int m = 0; m < 4; m++)
    #pragma unroll
    for (int q = 0; q < 4; q++) acc[m][q] = (f32x4){0.f,0.f,0.f,0.f};

  for (int ks = 0; ks < NKT; ks++){
    __syncthreads();
    #pragma unroll
    for (int j = 0; j < 4; j++){
      gl16(Ag + (size_t)(j*32 + srow)*(KT*2) + (size_t)ks*128 + scol, (char*)As + j*4096 + wub);
      gl16(Bg + (size_t)(j*32 + srow)*(KT*2) + (size_t)ks*128 + scol, (char*)Bs + j*4096 + wub);
    }
    __syncthreads();
    short8 af[2][4], bf[2][4];
    #pragma unroll
    for (int m = 0; m < 4; m++){
      af[0][m] = *(const short8*)((const char*)As + arow + m*2048 + cx0);
      af[1][m] = *(const short8*)((const char*)As + arow + m*2048 + cx1);
    }
    #pragma unroll
    for (int q = 0; q < 4; q++){
      bf[0][q] = *(const short8*)((const char*)Bs + brow + q*2048 + cx0);
      bf[1][q] = *(const short8*)((const char*)Bs + brow + q*2048 + cx1);
    }
    #pragma unroll
    for (int kk = 0; kk < 2; kk++)
      #pragma unroll
      for (int q = 0; q < 4; q++)
        #pragma unroll
        for (int m = 0; m < 4; m++)
          acc[m][q] = __builtin_amdgcn_mfma_f32_16x16x32_bf16(af[kk][m], bf[kk][q], acc[m][q], 0, 0, 0);
  }

  // epilogue: tanh+V reduce -> ered[wn][tl] (single writer per slot), then
  // wn-merge and one coalesced store per block (only rows t < xl are read).
  __syncthreads();                    // all LDS reads retired; reuse As
  float* ered = (float*)As;           // [2][128]
  #pragma unroll
  for (int m = 0; m < 4; m++){
    #pragma unroll
    for (int r = 0; r < 4; r++){
      float ps = 0.f;
      #pragma unroll
      for (int q = 0; q < 4; q++)
        ps = fmaf(pade_tanh(acc[m][q][r] + dv[q]), vv[q], ps);
      ROW16_SUM(ps);
      if ((lane & 15) == 0)
        ered[wn*128 + wm*64 + m*16 + (lane >> 4)*4 + r] = ps;
    }
  }
  __syncthreads();
  if (tid < 128){
    int t = trow + tid;
    if (t < xl)
      part[(((size_t)(nt & 3)*16 + b)*H_ + h)*TP + t] = ered[tid] + ered[128 + tid];
  }
}

// ---------------------------------------------------------------------------
// softmax over T per (b,h); 512 threads (latency-bound kernel: more TLP/ILP).
// Sums 4 coalesced partial slices, applies mask.
__global__ void k_softmax(const float* __restrict__ part, const int* __restrict__ x_lens,
                          float* __restrict__ aw){
  int h = blockIdx.x, b = blockIdx.y;
  __shared__ float sh[T_];
  __shared__ float red[16];
  int tid = threadIdx.x;   // 0..511, 8 waves
  int xl = x_lens[b];
  float mx = -1e30f;
  for (int t = tid; t < T_; t += 512){
    float e = 0.f;
    if (t < xl){
      e = part[(((size_t)0*16 + b)*H_ + h)*TP + t]
        + part[(((size_t)1*16 + b)*H_ + h)*TP + t]
        + part[(((size_t)2*16 + b)*H_ + h)*TP + t]
        + part[(((size_t)3*16 + b)*H_ + h)*TP + t];
    }
    sh[t] = e;
    mx = fmaxf(mx, e);
  }
  #pragma unroll
  for (int o = 32; o; o >>= 1) mx = fmaxf(mx, __shfl_xor(mx, o));
  if ((tid & 63) == 0) red[tid >> 6] = mx;
  __syncthreads();
  mx = fmaxf(fmaxf(fmaxf(red[0], red[1]), fmaxf(red[2], red[3])),
             fmaxf(fmaxf(red[4], red[5]), fmaxf(red[6], red[7])));
  float sm = 0.f;
  for (int t = tid; t < T_; t += 512){
    float ex = __expf(sh[t] - mx);
    sh[t] = ex;
    sm += ex;
  }
  #pragma unroll
  for (int o = 32; o; o >>= 1) sm += __shfl_xor(sm, o);
  if ((tid & 63) == 0) red[8 + (tid >> 6)] = sm;
  __syncthreads();
  sm = (red[8] + red[9]) + (red[10] + red[11]) + (red[12] + red[13]) + (red[14] + red[15]);
  float inv = 1.f / sm;
  for (int t = tid; t < T_; t += 512){
    aw[((size_t)b*T_ + t)*H_ + h] = sh[t] * inv;
  }
}

// ---------------------------------------------------------------------------
// partial context from bf16 Abf
#define CCH 125
__global__ void k_ctxp(const unsigned short* __restrict__ Abf, const float* __restrict__ aw,
                       float* __restrict__ ctxp){
  int ch = blockIdx.x, b = blockIdx.y;
  int t0 = ch * CCH;
  __shared__ float awl[CCH * 4];
  int tid = threadIdx.x;
  for (int i = tid; i < CCH*4; i += 256)
    awl[i] = aw[((size_t)b*T_ + t0)*H_ + i];
  __syncthreads();
  int e0 = tid * 2;
  float a0x=0,a0y=0,a1x=0,a1y=0,a2x=0,a2y=0,a3x=0,a3y=0;
  #pragma unroll 5
  for (int tl = 0; tl < CCH; tl++){
    uint uv = *(const uint*)&Abf[((size_t)b*MROWS + t0 + tl)*KT + e0];
    float evx = __uint_as_float(uv << 16);
    float evy = __uint_as_float(uv & 0xFFFF0000u);
    float w0 = awl[tl*4+0], w1 = awl[tl*4+1], w2 = awl[tl*4+2], w3 = awl[tl*4+3];
    a0x = fmaf(w0, evx, a0x); a0y = fmaf(w0, evy, a0y);
    a1x = fmaf(w1, evx, a1x); a1y = fmaf(w1, evy, a1y);
    a2x = fmaf(w2, evx, a2x); a2y = fmaf(w2, evy, a2y);
    a3x = fmaf(w3, evx, a3x); a3y = fmaf(w3, evy, a3y);
  }
  size_t base = ((size_t)(b*16) + ch) * (H_*E_);
  ctxp[base + 0*E_ + e0] = a0x; ctxp[base + 0*E_ + e0+1] = a0y;
  ctxp[base + 1*E_ + e0] = a1x; ctxp[base + 1*E_ + e0+1] = a1y;
  ctxp[base + 2*E_ + e0] = a2x; ctxp[base + 2*E_ + e0+1] = a2y;
  ctxp[base + 3*E_ + e0] = a3x; ctxp[base + 3*E_ + e0+1] = a3y;
}

// ---------------------------------------------------------------------------
// final GEMM: fpart[kq][b][eo] over he-slice; ch-sum of ctxp inlined in loader.
// grid (32 kq, 8 g); block computes 16 b x 64 eo. Wm read exactly once.
__global__ void k_fgemm(const float* __restrict__ ctxp, const float* __restrict__ Wm,
                        float* __restrict__ fpart){
  int kq = blockIdx.x, g = blockIdx.y;
  __shared__ float cpl[16][64];
  __shared__ float red[4][16][64];
  int tid = threadIdx.x;
  { // load + ch-reduce cpa slice: thread -> (b = tid>>4, i4 = (tid&15)*4)
    int b = tid >> 4, i4 = (tid & 15) * 4;
    const float* base = ctxp + (size_t)b*16*2048 + kq*64 + i4;
    float sx = 0.f, sy = 0.f, sz = 0.f, sw = 0.f;
    #pragma unroll
    for (int ch = 0; ch < 16; ch++){
      float4 v = *(const float4*)(base + (size_t)ch*2048);
      sx += v.x; sy += v.y; sz += v.z; sw += v.w;
    }
    cpl[b][i4] = sx; cpl[b][i4+1] = sy; cpl[b][i4+2] = sz; cpl[b][i4+3] = sw;
  }
  __syncthreads();
  int e = tid & 63, p = tid >> 6;
  float acc[16];
  #pragma unroll
  for (int b = 0; b < 16; b++) acc[b] = 0.f;
  #pragma unroll
  for (int i = 0; i < 16; i++){
    int he = kq*64 + p*16 + i;
    float wv = Wm[(size_t)he*512 + g*64 + e];
    #pragma unroll
    for (int b = 0; b < 16; b++)
      acc[b] = fmaf(cpl[b][p*16 + i], wv, acc[b]);
  }
  #pragma unroll
  for (int b = 0; b < 16; b++) red[p][b][e] = acc[b];
  __syncthreads();
  int bq = tid >> 6;          // 0..3
  #pragma unroll
  for (int j = 0; j < 4; j++){
    int b = bq*4 + j;
    float s = red[0][b][e] + red[1][b][e] + red[2][b][e] + red[3][b][e];
    fpart[(((size_t)kq*16) + b)*512 + g*64 + e] = s;
  }
}

// ---------------------------------------------------------------------------
// final reduce: out[b][eo] = bm[eo] + sum_kq fpart[kq][b][eo]; grid (16,2)
__global__ void k_fred(const float* __restrict__ fpart, const float* __restrict__ bm,
                       float* __restrict__ out){
  int b = blockIdx.x, qq = blockIdx.y, tid = threadIdx.x;
  int eo = qq*256 + tid;
  float acc = bm[eo];
  #pragma unroll 8
  for (int kq = 0; kq < 32; kq++)
    acc += fpart[(((size_t)kq*16) + b)*512 + eo];
  out[(size_t)b*512 + eo] = acc;
}

// ---------------------------------------------------------------------------
extern "C" void kernel_launch(void* const* d_in, const int* in_sizes, int n_in,
                              void* d_out, int out_size, void* d_ws, size_t ws_size,
                              hipStream_t stream){
  const float* enc    = (const float*)d_in[0];
  const int*   xl     = (const int*)  d_in[1];
  const float* dec    = (const float*)d_in[2];
  const float* awstep = (const float*)d_in[3];
  const float* We     = (const float*)d_in[4];
  const float* be     = (const float*)d_in[5];
  const float* Wd     = (const float*)d_in[6];
  const float* Wc     = (const float*)d_in[7];
  const float* convw  = (const float*)d_in[8];
  const float* Vv     = (const float*)d_in[9];
  const float* Wm     = (const float*)d_in[10];
  const float* bm     = (const float*)d_in[11];

  float* out_ctx = (float*)d_out;
  float* out_aw  = (float*)d_out + (size_t)B_ * E_;

  char* ws = (char*)d_ws;
  unsigned short* Wcomb = (unsigned short*)ws; ws += (size_t)2048*KT*2;        //  2,359,296
  unsigned short* Abf   = (unsigned short*)ws; ws += (size_t)B_*MROWS*KT*2;    // 37,748,736
  float* dech_p    = (float*)ws; ws += (size_t)4*64*512*4;                     //    524,288
  float* part      = (float*)ws; ws += (size_t)4*B_*H_*TP*4;                   //  2,097,152
  float* ctxp      = (float*)ws; ws += (size_t)B_*16*H_*E_*4;                  //  2,097,152
  float* fpart     = (float*)ws; ws += (size_t)32*B_*512*4;                    //  1,048,576

  k_pre    <<<dim3(3968),    dim3(256), 0, stream>>>(awstep, convw, We, Wc, Wcomb,
                                                     dec, Wd, be, dech_p, enc, Abf, xl);
  k_energy <<<dim3(4096),    dim3(256), 0, stream>>>(Abf, Wcomb, dech_p, Vv, xl, part);
  k_softmax<<<dim3(H_, B_),  dim3(512), 0, stream>>>(part, xl, out_aw);
  k_ctxp   <<<dim3(16, B_),  dim3(256), 0, stream>>>(Abf, out_aw, ctxp);
  k_fgemm  <<<dim3(32, 8),   dim3(256), 0, stream>>>(ctxp, Wm, fpart);
  k_fred   <<<dim3(B_, 2),   dim3(256), 0, stream>>>(fpart, bm, out_ctx);
}